// Round 6
// baseline (317.341 us; speedup 1.0000x reference)
//
#include <hip/hip_runtime.h>
#include <hip/hip_fp16.h>

#define NPTS 100000
#define NB 500
#define KNN 100
#define KPN 15
#define C1 128
#define C2 1024
#define C3 512
#define C4 256

typedef _Float16 half8 __attribute__((ext_vector_type(8)));
typedef float f32x4 __attribute__((ext_vector_type(4)));

// ---------------------------------------------------------------- kNN v4
// Q=2 queries per block share one stream of pts (halves L2 traffic).
// 2048-bin histogram (bits>>20) per query + exact rank-select on the
// boundary bin; per-query narrowing fallback (cold). Writes sel as well.
#define QB 2
#define KT 1024
#define CAP 768
#define HS 20
#define HBINS 2048

__device__ __forceinline__ unsigned linf_bits(float px, float py, float pz,
                                              float sx, float sy, float sz) {
  float dx = fabsf(px - sx), dy = fabsf(py - sy), dz = fabsf(pz - sz);
  return __float_as_uint(fmaxf(fmaxf(dx, dy), dz));
}

__global__ __launch_bounds__(KT) void knn_kernel(
    const float* __restrict__ pts, const int* __restrict__ index,
    float* __restrict__ sel, int* __restrict__ nbr) {
  const int b = blockIdx.x;  // queries 2b, 2b+1
  const int tid = threadIdx.x;
  __shared__ unsigned hist[QB * HBINS];  // reused as 4096 scratch in fallback
  __shared__ unsigned chunk[QB][256];
  __shared__ float qs[QB][3];
  __shared__ int s_kneed[QB], s_cnt[QB], s_shift[QB];
  __shared__ unsigned s_prefix[QB];
  __shared__ int s_direct[QB], s_cnt2[QB];
  __shared__ unsigned cand_bits[QB][CAP];
  __shared__ int cand_idx[QB][CAP];

  for (int j = tid; j < QB * HBINS; j += KT) hist[j] = 0;
  if (tid < QB * 3) {
    int q = tid / 3, c = tid % 3;
    float v = pts[3 * index[b * QB + q] + c];
    qs[q][c] = v;
    sel[(b * QB + q) * 3 + c] = v;
  }
  __syncthreads();
  const float sx0 = qs[0][0], sy0 = qs[0][1], sz0 = qs[0][2];
  const float sx1 = qs[1][0], sy1 = qs[1][1], sz1 = qs[1][2];
  const float4* base4 = (const float4*)pts;

  // ---- scan 1: dual-query histogram, 8 pts/thread, prefetched float4
  {
    float4 c6[6], n6[6];
    int i0 = tid * 8;
#pragma unroll
    for (int j = 0; j < 6; ++j) c6[j] = base4[(i0 * 3) / 4 + j];
    for (int it = 0; it < 12; ++it) {
      if (it + 1 < 12) {
        int i1 = (it + 1) * 8192 + tid * 8;
#pragma unroll
        for (int j = 0; j < 6; ++j) n6[j] = base4[(i1 * 3) / 4 + j];
      }
      float px[8], py[8], pz[8];
      px[0] = c6[0].x; py[0] = c6[0].y; pz[0] = c6[0].z;
      px[1] = c6[0].w; py[1] = c6[1].x; pz[1] = c6[1].y;
      px[2] = c6[1].z; py[2] = c6[1].w; pz[2] = c6[2].x;
      px[3] = c6[2].y; py[3] = c6[2].z; pz[3] = c6[2].w;
      px[4] = c6[3].x; py[4] = c6[3].y; pz[4] = c6[3].z;
      px[5] = c6[3].w; py[5] = c6[4].x; pz[5] = c6[4].y;
      px[6] = c6[4].z; py[6] = c6[4].w; pz[6] = c6[5].x;
      px[7] = c6[5].y; py[7] = c6[5].z; pz[7] = c6[5].w;
#pragma unroll
      for (int j = 0; j < 8; ++j) {
        unsigned b0 = linf_bits(px[j], py[j], pz[j], sx0, sy0, sz0);
        unsigned b1 = linf_bits(px[j], py[j], pz[j], sx1, sy1, sz1);
        atomicAdd(&hist[b0 >> HS], 1u);
        atomicAdd(&hist[HBINS + (b1 >> HS)], 1u);
      }
#pragma unroll
      for (int j = 0; j < 6; ++j) c6[j] = n6[j];
    }
    for (int i = 98304 + tid; i < NPTS; i += KT) {
      float px = pts[3 * i], py = pts[3 * i + 1], pz = pts[3 * i + 2];
      atomicAdd(&hist[linf_bits(px, py, pz, sx0, sy0, sz0) >> HS], 1u);
      atomicAdd(&hist[HBINS + (linf_bits(px, py, pz, sx1, sy1, sz1) >> HS)], 1u);
    }
  }
  __syncthreads();

  // ---- boundary per query
  if (tid < QB * 256) {
    int q = tid >> 8, c = tid & 255;
    unsigned s = 0;
    for (int j = 0; j < 8; ++j) s += hist[q * HBINS + c * 8 + j];
    chunk[q][c] = s;
  }
  __syncthreads();
  if (tid < QB) {
    int q = tid;
    unsigned need = KNN, cum = 0;
    int ch = 0;
    while (ch < 255 && cum + chunk[q][ch] < need) { cum += chunk[q][ch]; ++ch; }
    int bin = ch * 8;
    while (cum + hist[q * HBINS + bin] < need) {
      cum += hist[q * HBINS + bin];
      ++bin;
    }
    s_kneed[q] = (int)(need - cum);
    s_prefix[q] = (unsigned)bin;
    s_cnt[q] = (int)hist[q * HBINS + bin];
    s_shift[q] = HS;
    s_direct[q] = 0;
    s_cnt2[q] = 0;
  }

  // ---- cold fallback: narrow an overfull boundary bin (scratch = hist)
  for (int q = 0; q < QB; ++q) {
    for (;;) {
      __syncthreads();
      if (s_cnt[q] <= CAP || s_shift[q] == 0) break;
      const int fsh = s_shift[q];
      const unsigned pfx = s_prefix[q];
      const int nsh = (fsh == HS) ? 8 : 0;
      const int nb = (fsh == HS) ? 4096 : 256;
      const float qx = qs[q][0], qy = qs[q][1], qz = qs[q][2];
      for (int j = tid; j < nb; j += KT) hist[j] = 0;
      __syncthreads();
      for (int i = tid; i < NPTS; i += KT) {
        unsigned bits =
            linf_bits(pts[3 * i], pts[3 * i + 1], pts[3 * i + 2], qx, qy, qz);
        if ((bits >> fsh) == pfx) atomicAdd(&hist[(bits >> nsh) & (nb - 1)], 1u);
      }
      __syncthreads();
      if (tid == 0) {
        unsigned need = (unsigned)s_kneed[q], cum = 0;
        int bin = 0;
        while (cum + hist[bin] < need) { cum += hist[bin]; ++bin; }
        s_kneed[q] = (int)(need - cum);
        s_cnt[q] = (int)hist[bin];
        s_prefix[q] = (pfx << ((fsh == HS) ? 12 : 8)) | (unsigned)bin;
        s_shift[q] = nsh;
      }
    }
  }
  __syncthreads();
  const int sh0 = s_shift[0], sh1 = s_shift[1];
  const unsigned pf0 = s_prefix[0], pf1 = s_prefix[1];

  // ---- scan 2: collect members + boundary candidates for both queries
  {
    float4 c6[6], n6[6];
    int i0 = tid * 8;
#pragma unroll
    for (int j = 0; j < 6; ++j) c6[j] = base4[(i0 * 3) / 4 + j];
    for (int it = 0; it < 12; ++it) {
      if (it + 1 < 12) {
        int i1 = (it + 1) * 8192 + tid * 8;
#pragma unroll
        for (int j = 0; j < 6; ++j) n6[j] = base4[(i1 * 3) / 4 + j];
      }
      float px[8], py[8], pz[8];
      px[0] = c6[0].x; py[0] = c6[0].y; pz[0] = c6[0].z;
      px[1] = c6[0].w; py[1] = c6[1].x; pz[1] = c6[1].y;
      px[2] = c6[1].z; py[2] = c6[1].w; pz[2] = c6[2].x;
      px[3] = c6[2].y; py[3] = c6[2].z; pz[3] = c6[2].w;
      px[4] = c6[3].x; py[4] = c6[3].y; pz[4] = c6[3].z;
      px[5] = c6[3].w; py[5] = c6[4].x; pz[5] = c6[4].y;
      px[6] = c6[4].z; py[6] = c6[4].w; pz[6] = c6[5].x;
      px[7] = c6[5].y; py[7] = c6[5].z; pz[7] = c6[5].w;
      int ibase = it * 8192 + tid * 8;
#pragma unroll
      for (int j = 0; j < 8; ++j) {
        unsigned b0 = linf_bits(px[j], py[j], pz[j], sx0, sy0, sz0);
        unsigned b1 = linf_bits(px[j], py[j], pz[j], sx1, sy1, sz1);
        unsigned v0 = b0 >> sh0, v1 = b1 >> sh1;
        if (v0 < pf0) {
          int pos = atomicAdd(&s_direct[0], 1);
          nbr[(b * QB + 0) * KNN + pos] = ibase + j;
        } else if (v0 == pf0) {
          int e = atomicAdd(&s_cnt2[0], 1);
          if (e < CAP) { cand_bits[0][e] = b0; cand_idx[0][e] = ibase + j; }
        }
        if (v1 < pf1) {
          int pos = atomicAdd(&s_direct[1], 1);
          nbr[(b * QB + 1) * KNN + pos] = ibase + j;
        } else if (v1 == pf1) {
          int e = atomicAdd(&s_cnt2[1], 1);
          if (e < CAP) { cand_bits[1][e] = b1; cand_idx[1][e] = ibase + j; }
        }
      }
#pragma unroll
      for (int j = 0; j < 6; ++j) c6[j] = n6[j];
    }
    for (int i = 98304 + tid; i < NPTS; i += KT) {
      float px = pts[3 * i], py = pts[3 * i + 1], pz = pts[3 * i + 2];
      unsigned b0 = linf_bits(px, py, pz, sx0, sy0, sz0);
      unsigned b1 = linf_bits(px, py, pz, sx1, sy1, sz1);
      unsigned v0 = b0 >> sh0, v1 = b1 >> sh1;
      if (v0 < pf0) {
        int pos = atomicAdd(&s_direct[0], 1);
        nbr[(b * QB + 0) * KNN + pos] = i;
      } else if (v0 == pf0) {
        int e = atomicAdd(&s_cnt2[0], 1);
        if (e < CAP) { cand_bits[0][e] = b0; cand_idx[0][e] = i; }
      }
      if (v1 < pf1) {
        int pos = atomicAdd(&s_direct[1], 1);
        nbr[(b * QB + 1) * KNN + pos] = i;
      } else if (v1 == pf1) {
        int e = atomicAdd(&s_cnt2[1], 1);
        if (e < CAP) { cand_bits[1][e] = b1; cand_idx[1][e] = i; }
      }
    }
  }
  __syncthreads();

  // ---- exact rank-select among candidates (ties: lowest index == top_k)
  for (int q = 0; q < QB; ++q) {
    int m = s_cnt2[q] < CAP ? s_cnt2[q] : CAP;
    int base = s_direct[q];
    int kneedq = s_kneed[q];
    for (int c = tid; c < m; c += KT) {
      unsigned bc = cand_bits[q][c];
      int ic = cand_idx[q][c];
      int rank = 0;
      for (int j = 0; j < m; ++j) {
        unsigned bj = cand_bits[q][j];
        rank += (bj < bc || (bj == bc && cand_idx[q][j] < ic)) ? 1 : 0;
      }
      if (rank < kneedq) nbr[(b * QB + q) * KNN + base + rank] = ic;
    }
  }
}

// ------------------------------------------------- converts + normal gather
__global__ __launch_bounds__(256) void convert_kernel(
    const float* __restrict__ w1, const float* __restrict__ kpw,
    const float* __restrict__ normal, const int* __restrict__ index,
    __half* __restrict__ wh, __half* __restrict__ kpwT_hi,
    __half* __restrict__ kpwT_lo, float* __restrict__ out2) {
  int i = blockIdx.x * 256 + threadIdx.x;
  if (i < C2 * C1) wh[i] = __float2half(w1[i]);
  if (i < 128 * 64) {
    int o = i >> 6, j = i & 63;
    float v = (j < 45) ? kpw[j * 128 + o] : 0.f;
    __half hi = __float2half_rn(v);
    kpwT_hi[i] = hi;
    kpwT_lo[i] = __float2half_rn(v - __half2float(hi));
  }
  if (i < NB * 3) {
    int b = i / 3, c = i % 3;
    out2[i] = normal[3 * index[b] + c];
  }
}

// ------------------------------------------------- KPConv (f16 MFMA, hi/lo)
__global__ __launch_bounds__(256) void kpconv_mfma_kernel(
    const float* __restrict__ pts, const float* __restrict__ sel,
    const int* __restrict__ nbr, const float* __restrict__ kp_points,
    const __half* __restrict__ kpwT_hi, const __half* __restrict__ kpwT_lo,
    const float* __restrict__ kp_sigma, __half* __restrict__ h) {
  const int b = blockIdx.x;
  const int tid = threadIdx.x;
  const int wave = tid >> 6, lane = tid & 63;
  const int lr = lane & 15, quad = lane >> 4;
  __shared__ __half As_hi[112 * 72];
  __shared__ __half As_lo[112 * 72];
  __shared__ __half Bs_hi[128 * 72];
  __shared__ __half Bs_lo[128 * 72];
  __shared__ float rel[100][4];
  __shared__ float kpp[48];

  for (int i = tid; i < 128 * 8; i += 256) {
    int row = i >> 3, seg = i & 7;
    *(float4*)&Bs_hi[row * 72 + seg * 8] =
        *(const float4*)&kpwT_hi[row * 64 + seg * 8];
    *(float4*)&Bs_lo[row * 72 + seg * 8] =
        *(const float4*)&kpwT_lo[row * 64 + seg * 8];
  }
  {
    float4 z = make_float4(0.f, 0.f, 0.f, 0.f);
    for (int i = tid; i < 112 * 8; i += 256) {
      int row = i >> 3, seg = i & 7;
      *(float4*)&As_hi[row * 72 + seg * 8] = z;
      *(float4*)&As_lo[row * 72 + seg * 8] = z;
    }
  }
  if (tid < 45) kpp[tid] = kp_points[tid];
  if (tid < 100) {
    int idx = nbr[b * KNN + tid];
    rel[tid][0] = pts[3 * idx + 0] - sel[b * 3 + 0];
    rel[tid][1] = pts[3 * idx + 1] - sel[b * 3 + 1];
    rel[tid][2] = pts[3 * idx + 2] - sel[b * 3 + 2];
  }
  __syncthreads();

  const float sg = kp_sigma[0];
  const float inv2s2 = -0.5f / (sg * sg);
  for (int i = tid; i < 100 * KPN; i += 256) {
    int k = i / KPN, p = i - k * KPN;
    float rx = rel[k][0] - kpp[p * 3 + 0];
    float ry = rel[k][1] - kpp[p * 3 + 1];
    float rz = rel[k][2] - kpp[p * 3 + 2];
    float w = expf(inv2s2 * (rx * rx + ry * ry + rz * rz));
#pragma unroll
    for (int c = 0; c < 3; ++c) {
      float a = rel[k][c] * w;
      __half hi = __float2half_rn(a);
      As_hi[k * 72 + p * 3 + c] = hi;
      As_lo[k * 72 + p * 3 + c] = __float2half_rn(a - __half2float(hi));
    }
  }
  __syncthreads();

  f32x4 acc[2][7];
#pragma unroll
  for (int t = 0; t < 2; ++t)
#pragma unroll
    for (int m = 0; m < 7; ++m) acc[t][m] = (f32x4)(0.f);

#pragma unroll
  for (int s = 0; s < 2; ++s) {
    half8 bhi[2], blo[2];
#pragma unroll
    for (int t = 0; t < 2; ++t) {
      int boff = ((wave * 2 + t) * 16 + lr) * 72 + s * 32 + quad * 8;
      bhi[t] = *(const half8*)&Bs_hi[boff];
      blo[t] = *(const half8*)&Bs_lo[boff];
    }
#pragma unroll
    for (int m = 0; m < 7; ++m) {
      int aoff = (m * 16 + lr) * 72 + s * 32 + quad * 8;
      half8 ahi = *(const half8*)&As_hi[aoff];
      half8 alo = *(const half8*)&As_lo[aoff];
#pragma unroll
      for (int t = 0; t < 2; ++t) {
        acc[t][m] = __builtin_amdgcn_mfma_f32_16x16x32_f16(ahi, bhi[t],
                                                           acc[t][m], 0, 0, 0);
        acc[t][m] = __builtin_amdgcn_mfma_f32_16x16x32_f16(ahi, blo[t],
                                                           acc[t][m], 0, 0, 0);
        acc[t][m] = __builtin_amdgcn_mfma_f32_16x16x32_f16(alo, bhi[t],
                                                           acc[t][m], 0, 0, 0);
      }
    }
  }

#pragma unroll
  for (int t = 0; t < 2; ++t) {
    int col = (wave * 2 + t) * 16 + lr;
#pragma unroll
    for (int m = 0; m < 7; ++m)
#pragma unroll
      for (int r = 0; r < 4; ++r) {
        int row = m * 16 + quad * 4 + r;
        if (row < 100)
          h[(b * KNN + row) * 128 + col] =
              __float2half_rn(fmaxf(acc[t][m][r], 0.f));
      }
  }
}

// ------------------------------------------------------- conv1 (f16 MFMA)
__global__ __launch_bounds__(256) void conv1_mfma_kernel(
    const __half* __restrict__ h16, const __half* __restrict__ wh,
    const float* __restrict__ bias, float* __restrict__ featmax,
    float* __restrict__ featmin, float* __restrict__ bnsum,
    float* __restrict__ bnsq) {
  const int b = blockIdx.y;
  const int n0 = blockIdx.x * 128;
  const int tid = threadIdx.x;
  const int wave = tid >> 6, lane = tid & 63;
  const int lr = lane & 15, quad = lane >> 4;
  __shared__ __half Hs[112 * 136];
  __shared__ __half Ws[128 * 136];

  for (int i = tid; i < 112 * 16; i += 256) {
    int row = i >> 4, seg = i & 15;
    float4 v = make_float4(0.f, 0.f, 0.f, 0.f);
    if (row < 100) v = *(const float4*)&h16[(b * 100 + row) * 128 + seg * 8];
    *(float4*)&Hs[row * 136 + seg * 8] = v;
  }
  for (int i = tid; i < 128 * 16; i += 256) {
    int row = i >> 4, seg = i & 15;
    *(float4*)&Ws[row * 136 + seg * 8] =
        *(const float4*)&wh[(n0 + row) * 128 + seg * 8];
  }
  __syncthreads();

  f32x4 acc[2][7];
#pragma unroll
  for (int t = 0; t < 2; ++t)
#pragma unroll
    for (int m = 0; m < 7; ++m) acc[t][m] = (f32x4)(0.f);

#pragma unroll
  for (int s = 0; s < 4; ++s) {
    half8 bfrag[2];
#pragma unroll
    for (int t = 0; t < 2; ++t)
      bfrag[t] =
          *(const half8*)&Ws[((wave * 2 + t) * 16 + lr) * 136 + s * 32 + quad * 8];
#pragma unroll
    for (int m = 0; m < 7; ++m) {
      half8 afrag = *(const half8*)&Hs[(m * 16 + lr) * 136 + s * 32 + quad * 8];
      acc[0][m] =
          __builtin_amdgcn_mfma_f32_16x16x32_f16(afrag, bfrag[0], acc[0][m], 0, 0, 0);
      acc[1][m] =
          __builtin_amdgcn_mfma_f32_16x16x32_f16(afrag, bfrag[1], acc[1][m], 0, 0, 0);
    }
  }

#pragma unroll
  for (int t = 0; t < 2; ++t) {
    int col = n0 + (wave * 2 + t) * 16 + lr;
    float bv = bias[col];
    float pmax = -1e30f, pmin = 1e30f, psum = 0.f, psq = 0.f;
#pragma unroll
    for (int m = 0; m < 7; ++m)
#pragma unroll
      for (int r = 0; r < 4; ++r) {
        int row = m * 16 + quad * 4 + r;
        if (row < 100) {
          float y = fmaxf(acc[t][m][r] + bv, 0.f);
          pmax = fmaxf(pmax, y);
          pmin = fminf(pmin, y);
          psum += y;
          psq += y * y;
        }
      }
    pmax = fmaxf(pmax, __shfl_xor(pmax, 16));
    pmax = fmaxf(pmax, __shfl_xor(pmax, 32));
    pmin = fminf(pmin, __shfl_xor(pmin, 16));
    pmin = fminf(pmin, __shfl_xor(pmin, 32));
    psum += __shfl_xor(psum, 16);
    psum += __shfl_xor(psum, 32);
    psq += __shfl_xor(psq, 16);
    psq += __shfl_xor(psq, 32);
    if (quad == 0) {
      featmax[b * C2 + col] = pmax;
      featmin[b * C2 + col] = pmin;
      atomicAdd(&bnsum[col], psum);
      atomicAdd(&bnsq[col], psq);
    }
  }
}

// ----------------------------------- fc with fused input-BN + relu + stats
// MODE 1: input = BN1(featmax/featmin select by sign(a)), count NB*KNN
// MODE 2: input = BN(x1), count NB
template <int KDIM, int MODE>
__global__ __launch_bounds__(256) void fc_bn_relu_stats_kernel(
    const float* __restrict__ x1, const float* __restrict__ x2,
    const float* __restrict__ sstat, const float* __restrict__ sqstat,
    const float* __restrict__ bng, const float* __restrict__ bnb,
    const float* __restrict__ w, const float* __restrict__ bias,
    float* __restrict__ yraw, float* __restrict__ s, float* __restrict__ sq,
    int ncols) {
  const int r0 = blockIdx.x * 4;
  const int n0 = blockIdx.y * 64;
  const int tid = threadIdx.x;
  const int col = tid >> 2;
  const int row = tid & 3;
  __shared__ float xs[4][KDIM + 4];
  __shared__ float ws[64][132];
  __shared__ float ao[KDIM], off[KDIM];
  const float invn = (MODE == 1) ? (1.f / (float)(NB * KNN)) : (1.f / (float)NB);
  for (int k = tid; k < KDIM; k += 256) {
    float m = sstat[k] * invn;
    float v = sqstat[k] * invn - m * m;
    float a = bng[k] / sqrtf(v + 1e-5f);
    ao[k] = a;
    off[k] = bnb[k] - m * a;
  }
  __syncthreads();
  for (int f = tid; f < KDIM; f += 256) {
    int rr = f / (KDIM / 4), kq = (f % (KDIM / 4)) * 4;
    float4 xm = *(const float4*)&x1[(r0 + rr) * KDIM + kq];
    float v1[4] = {xm.x, xm.y, xm.z, xm.w};
    if constexpr (MODE == 1) {
      float4 xn = *(const float4*)&x2[(r0 + rr) * KDIM + kq];
      float v2[4] = {xn.x, xn.y, xn.z, xn.w};
#pragma unroll
      for (int j = 0; j < 4; ++j) {
        float a = ao[kq + j];
        float x = (a >= 0.f) ? v1[j] : v2[j];
        xs[rr][kq + j] = x * a + off[kq + j];
      }
    } else {
#pragma unroll
      for (int j = 0; j < 4; ++j)
        xs[rr][kq + j] = v1[j] * ao[kq + j] + off[kq + j];
    }
  }
  float acc = 0.f;
  for (int kc = 0; kc < KDIM; kc += 128) {
    __syncthreads();
#pragma unroll
    for (int i = 0; i < 8; ++i) {
      int f = tid + i * 256;
      int cr = f >> 5, kq = (f & 31) * 4;
      *(float4*)&ws[cr][kq] = *(const float4*)&w[(n0 + cr) * KDIM + kc + kq];
    }
    __syncthreads();
    for (int kk = 0; kk < 128; kk += 4) {
      float4 xv = *(float4*)&xs[row][kc + kk];
      float4 wv = *(float4*)&ws[col][kk];
      acc += xv.x * wv.x + xv.y * wv.y + xv.z * wv.z + xv.w * wv.w;
    }
  }
  float y = fmaxf(acc + bias[n0 + col], 0.f);
  yraw[(r0 + row) * ncols + n0 + col] = y;
  float ys = y, y2 = y * y;
  ys += __shfl_xor(ys, 1); y2 += __shfl_xor(y2, 1);
  ys += __shfl_xor(ys, 2); y2 += __shfl_xor(y2, 2);
  if (row == 0) {
    atomicAdd(&s[n0 + col], ys);
    atomicAdd(&sq[n0 + col], y2);
  }
}

// ------------------------------------------------- fc3 with fused input-BN
__global__ __launch_bounds__(256) void fc3_bn_kernel(
    const float* __restrict__ f3raw, const float* __restrict__ s5,
    const float* __restrict__ sq5, const float* __restrict__ g5,
    const float* __restrict__ b5, const float* __restrict__ w,
    const float* __restrict__ bias, float* __restrict__ out) {
  __shared__ float ao[C4], off[C4];
  int tid = threadIdx.x;
  {
    float m = s5[tid] * (1.f / (float)NB);
    float v = sq5[tid] * (1.f / (float)NB) - m * m;
    float a = g5[tid] / sqrtf(v + 1e-5f);
    ao[tid] = a;
    off[tid] = b5[tid] - m * a;
  }
  __syncthreads();
  int idx = blockIdx.x * 256 + tid;
  if (idx >= NB * 3) return;
  int b = idx / 3, o = idx % 3;
  float acc = 0.f;
  for (int k = 0; k < C4; ++k)
    acc += (f3raw[b * C4 + k] * ao[k] + off[k]) * w[o * C4 + k];
  out[idx] = acc + bias[o];
}

// ---------------------------------------------------------------- launch
extern "C" void kernel_launch(void* const* d_in, const int* in_sizes, int n_in,
                              void* d_out, int out_size, void* d_ws,
                              size_t ws_size, hipStream_t stream) {
  const float* pts = (const float*)d_in[0];
  const float* normal = (const float*)d_in[1];
  const float* kp_points = (const float*)d_in[2];
  const float* kp_weights = (const float*)d_in[3];
  const float* kp_sigma = (const float*)d_in[4];
  const float* conv1_w = (const float*)d_in[5];
  const float* conv1_b = (const float*)d_in[6];
  const float* bn1_g = (const float*)d_in[7];
  const float* bn1_b = (const float*)d_in[8];
  const float* fc1_w = (const float*)d_in[9];
  const float* fc1_b = (const float*)d_in[10];
  const float* bn4_g = (const float*)d_in[11];
  const float* bn4_b = (const float*)d_in[12];
  const float* fc2_w = (const float*)d_in[13];
  const float* fc2_b = (const float*)d_in[14];
  const float* bn5_g = (const float*)d_in[15];
  const float* bn5_b = (const float*)d_in[16];
  const float* fc3_w = (const float*)d_in[17];
  const float* fc3_b = (const float*)d_in[18];
  const int* index = (const int*)d_in[19];
  float* out = (float*)d_out;

  char* p = (char*)d_ws;
  auto carve = [&](size_t bytes) {
    void* r = (void*)p;
    p += (bytes + 255) & ~(size_t)255;
    return r;
  };
  float* sel = (float*)carve(NB * 3 * 4);
  int* nbr = (int*)carve(NB * KNN * 4);
  __half* h = (__half*)carve((size_t)NB * KNN * C1 * 2);
  __half* wh = (__half*)carve((size_t)C2 * C1 * 2);
  __half* kpwT_hi = (__half*)carve((size_t)128 * 64 * 2);
  __half* kpwT_lo = (__half*)carve((size_t)128 * 64 * 2);
  float* featmax = (float*)carve(NB * C2 * 4);
  float* featmin = (float*)carve(NB * C2 * 4);
  float* f2raw = (float*)carve(NB * C3 * 4);
  float* f3raw = (float*)carve(NB * C4 * 4);
  float* stats = (float*)carve((2 * C2 + 2 * C3 + 2 * C4) * 4);
  float* bnsum = stats;
  float* bnsq = stats + C2;
  float* s4 = stats + 2 * C2;
  float* sq4 = s4 + C3;
  float* s5 = sq4 + C3;
  float* sq5 = s5 + C4;

  hipMemsetAsync(stats, 0, (2 * C2 + 2 * C3 + 2 * C4) * 4, stream);

  knn_kernel<<<NB / QB, KT, 0, stream>>>(pts, index, sel, nbr);
  convert_kernel<<<(C2 * C1 + 255) / 256, 256, 0, stream>>>(
      conv1_w, kp_weights, normal, index, wh, kpwT_hi, kpwT_lo, out + NB * 3);
  kpconv_mfma_kernel<<<NB, 256, 0, stream>>>(pts, sel, nbr, kp_points, kpwT_hi,
                                             kpwT_lo, kp_sigma, h);
  conv1_mfma_kernel<<<dim3(8, NB), 256, 0, stream>>>(h, wh, conv1_b, featmax,
                                                     featmin, bnsum, bnsq);
  fc_bn_relu_stats_kernel<C2, 1><<<dim3(125, C3 / 64), 256, 0, stream>>>(
      featmax, featmin, bnsum, bnsq, bn1_g, bn1_b, fc1_w, fc1_b, f2raw, s4,
      sq4, C3);
  fc_bn_relu_stats_kernel<C3, 2><<<dim3(125, C4 / 64), 256, 0, stream>>>(
      f2raw, nullptr, s4, sq4, bn4_g, bn4_b, fc2_w, fc2_b, f3raw, s5, sq5, C4);
  fc3_bn_kernel<<<(NB * 3 + 255) / 256, 256, 0, stream>>>(
      f3raw, s5, sq5, bn5_g, bn5_b, fc3_w, fc3_b, out);
}